// Round 8
// baseline (222.562 us; speedup 1.0000x reference)
//
#include <hip/hip_runtime.h>
#include <math.h>

#define BLOCK 256
#define FPC   256                 // frames per chunk, one frame per thread
#define F4M   (FPC * 9 / 4)       // 576 float4 per rot matrix per chunk
#define NBLOCKS 2048              // 8 blocks/CU x 256 CU, all resident

#define GLOAD_LDS16(gp, lp)                                                     \
  __builtin_amdgcn_global_load_lds(                                             \
      (const __attribute__((address_space(1))) void*)(gp),                      \
      (__attribute__((address_space(3))) void*)(lp), 16, 0, 0)

__global__ __launch_bounds__(BLOCK, 8) void rmse_partial_kernel(
    const float* __restrict__ rot_kf, const float* __restrict__ pose_kf,
    const float* __restrict__ rot_gt, const float* __restrict__ pose_gt,
    int* __restrict__ counter, float* __restrict__ partial, int N)
{
    // A and B staged together: 2 x 9216 B = 18432 B -> 8 blocks/CU
    __shared__ float ldsA[FPC * 9];
    __shared__ float ldsB[FPC * 9];
    __shared__ float redbuf[BLOCK / 64];
    __shared__ int   nextc;

    const int tid = threadIdx.x;
    const long long totalRotF = (long long)N * 9;
    const long long rotF4max = (totalRotF >= 4) ? (totalRotF - 4) / 4 : 0;
    const int nChunks = (int)(((long long)N + FPC - 1) / FPC);

    float sum = 0.0f;

    // get first chunk id
    if (tid == 0) nextc = atomicAdd(counter, 1);
    __syncthreads();
    int c = nextc;

    while (c < nChunks) {
        const long long base4 = (long long)c * F4M;

        // ---- stage both matrices via global_load_lds (no VGPR round-trip) ----
        for (int i = tid; i < F4M; i += BLOCK) {
            long long f4 = base4 + i;
            if (f4 > rotF4max) f4 = rotF4max;   // tail clamp; masked in compute
            GLOAD_LDS16(reinterpret_cast<const float4*>(rot_kf) + f4,
                        (void*)(reinterpret_cast<float4*>(ldsA) + i));
        }
        for (int i = tid; i < F4M; i += BLOCK) {
            long long f4 = base4 + i;
            if (f4 > rotF4max) f4 = rotF4max;
            GLOAD_LDS16(reinterpret_cast<const float4*>(rot_gt) + f4,
                        (void*)(reinterpret_cast<float4*>(ldsB) + i));
        }
        // prefetch next chunk id; atomic latency overlaps the staging loads
        if (tid == 0) nextc = atomicAdd(counter, 1);
        __syncthreads();   // drains vmcnt (stage landed) and lgkm (atomic landed)

        const int f = c * FPC + tid;
        if (f < N) {
            float a[9], b[9];
            #pragma unroll
            for (int j = 0; j < 9; ++j) a[j] = ldsA[tid * 9 + j];
            #pragma unroll
            for (int j = 0; j < 9; ++j) b[j] = ldsB[tid * 9 + j];

            const long long p = (long long)f * 3;
            const float d0 = pose_gt[p + 0] - pose_kf[p + 0];
            const float d1 = pose_gt[p + 1] - pose_kf[p + 1];
            const float d2 = pose_gt[p + 2] - pose_kf[p + 2];

            float se = 0.0f;
            #pragma unroll
            for (int i = 0; i < 3; ++i) {
                #pragma unroll
                for (int k = 0; k < 3; ++k) {
                    // R_rel[i][k] = sum_j A[j][i] * B[j][k]
                    float r = a[i] * b[k] + a[3 + i] * b[3 + k] + a[6 + i] * b[6 + k];
                    r -= (i == k) ? 1.0f : 0.0f;
                    se += r * r;
                }
                const float t = a[i] * d0 + a[3 + i] * d1 + a[6 + i] * d2;
                se += t * t;
            }
            sum += se;
        }

        const int cn = nextc;     // safe: next write is after next __syncthreads
        __syncthreads();          // protect LDS reads before restage
        c = cn;
    }

    // ---- block reduction ----
    const int lane = tid & 63;
    const int wave = tid >> 6;
    #pragma unroll
    for (int off = 32; off > 0; off >>= 1) sum += __shfl_down(sum, off);
    if (lane == 0) redbuf[wave] = sum;
    __syncthreads();
    if (tid == 0) {
        float s = 0.0f;
        #pragma unroll
        for (int w = 0; w < BLOCK / 64; ++w) s += redbuf[w];
        partial[blockIdx.x] = s;
    }
}

__global__ __launch_bounds__(BLOCK) void rmse_finalize_kernel(
    const float* __restrict__ partial, int nPartial, float* __restrict__ out, int N)
{
    __shared__ float redbuf[BLOCK / 64];
    float sum = 0.0f;
    for (int i = threadIdx.x; i < nPartial; i += BLOCK) sum += partial[i];
    #pragma unroll
    for (int off = 32; off > 0; off >>= 1) sum += __shfl_down(sum, off);
    const int lane = threadIdx.x & 63;
    const int wave = threadIdx.x >> 6;
    if (lane == 0) redbuf[wave] = sum;
    __syncthreads();
    if (threadIdx.x == 0) {
        float s = 0.0f;
        #pragma unroll
        for (int w = 0; w < BLOCK / 64; ++w) s += redbuf[w];
        out[0] = sqrtf(s / (float)N) + 1e-8f;
    }
}

extern "C" void kernel_launch(void* const* d_in, const int* in_sizes, int n_in,
                              void* d_out, int out_size, void* d_ws, size_t ws_size,
                              hipStream_t stream) {
    const float* rot_kf  = (const float*)d_in[0];
    const float* pose_kf = (const float*)d_in[1];
    const float* rot_gt  = (const float*)d_in[2];
    const float* pose_gt = (const float*)d_in[3];
    float* out = (float*)d_out;

    int*   counter = (int*)d_ws;
    float* partial = (float*)((char*)d_ws + 256);

    const int N = in_sizes[1] / 3;   // pose_kf is [N,3]
    const int nChunks = (int)(((long long)N + FPC - 1) / FPC);

    int grid = NBLOCKS;
    if (grid > nChunks) grid = nChunks;
    const int wsCap = (int)((ws_size - 256) / sizeof(float));
    if (grid > wsCap) grid = wsCap;
    if (grid < 1) grid = 1;

    hipMemsetAsync(counter, 0, sizeof(int), stream);
    rmse_partial_kernel<<<grid, BLOCK, 0, stream>>>(rot_kf, pose_kf, rot_gt, pose_gt,
                                                    counter, partial, N);
    rmse_finalize_kernel<<<1, BLOCK, 0, stream>>>(partial, grid, out, N);
}

// Round 9
// 71.965 us; speedup vs baseline: 3.0926x; 3.0926x over previous
//
#include <hip/hip_runtime.h>
#include <math.h>

#define BLOCK 256
#define GPC   64                  // 4-frame groups per chunk -> 256 frames/chunk
#define NBLOCKS 2048              // 8 blocks/CU x 256 CU, all resident

__global__ __launch_bounds__(BLOCK, 8) void rmse_partial_kernel(
    const float* __restrict__ rot_kf, const float* __restrict__ pose_kf,
    const float* __restrict__ rot_gt, const float* __restrict__ pose_gt,
    float* __restrict__ partial, int N)
{
    // 2 x 9216 B staging -> 8 blocks/CU (32 waves/CU)
    __shared__ float ldsA[GPC * 4 * 9];
    __shared__ float ldsB[GPC * 4 * 9];
    __shared__ float redbuf[BLOCK / 64];

    const int tid = threadIdx.x;
    const int G = N >> 2;                       // complete 4-frame groups

    // contiguous group-range per block: q or q+1 groups, imbalance <= 1 group
    const int q = G / gridDim.x;
    const int r = G % gridDim.x;
    const int bid = blockIdx.x;
    const long long gBeg = (long long)bid * q + (bid < r ? bid : r);
    const long long gEnd = gBeg + q + (bid < r ? 1 : 0);

    float sum = 0.0f;

    for (long long g0 = gBeg; g0 < gEnd; g0 += GPC) {
        const int grp    = (int)((gEnd - g0 < GPC) ? (gEnd - g0) : GPC);
        const int nF4    = grp * 9;             // float4 per matrix this chunk
        const int frames = grp * 4;
        const long long base4 = g0 * 9;         // float4 index (ranges are 9-f4 aligned)

        __syncthreads();   // protect LDS reads of previous iteration

        for (int i = tid; i < nF4; i += BLOCK)
            reinterpret_cast<float4*>(ldsA)[i] =
                reinterpret_cast<const float4*>(rot_kf)[base4 + i];
        for (int i = tid; i < nF4; i += BLOCK)
            reinterpret_cast<float4*>(ldsB)[i] =
                reinterpret_cast<const float4*>(rot_gt)[base4 + i];
        __syncthreads();

        if (tid < frames) {
            const long long f = g0 * 4 + tid;
            float a[9], b[9];
            #pragma unroll
            for (int j = 0; j < 9; ++j) a[j] = ldsA[tid * 9 + j];
            #pragma unroll
            for (int j = 0; j < 9; ++j) b[j] = ldsB[tid * 9 + j];

            const long long p = f * 3;
            const float d0 = pose_gt[p + 0] - pose_kf[p + 0];
            const float d1 = pose_gt[p + 1] - pose_kf[p + 1];
            const float d2 = pose_gt[p + 2] - pose_kf[p + 2];

            float se = 0.0f;
            #pragma unroll
            for (int i = 0; i < 3; ++i) {
                #pragma unroll
                for (int k = 0; k < 3; ++k) {
                    // R_rel[i][k] = sum_j A[j][i] * B[j][k]
                    float rr = a[i] * b[k] + a[3 + i] * b[3 + k] + a[6 + i] * b[6 + k];
                    rr -= (i == k) ? 1.0f : 0.0f;
                    se += rr * rr;
                }
                const float t = a[i] * d0 + a[3 + i] * d1 + a[6 + i] * d2;
                se += t * t;
            }
            sum += se;
        }
    }

    // ragged N%4 tail (0 for N=4M): last block, thread 0, scalar
    if (bid == (int)gridDim.x - 1 && tid == 0) {
        for (long long f = (long long)G * 4; f < N; ++f) {
            float a[9], b[9];
            for (int j = 0; j < 9; ++j) { a[j] = rot_kf[f * 9 + j]; b[j] = rot_gt[f * 9 + j]; }
            const long long p = f * 3;
            const float d0 = pose_gt[p+0] - pose_kf[p+0];
            const float d1 = pose_gt[p+1] - pose_kf[p+1];
            const float d2 = pose_gt[p+2] - pose_kf[p+2];
            float se = 0.0f;
            for (int i = 0; i < 3; ++i) {
                for (int k = 0; k < 3; ++k) {
                    float rr = a[i]*b[k] + a[3+i]*b[3+k] + a[6+i]*b[6+k];
                    rr -= (i == k) ? 1.0f : 0.0f;
                    se += rr * rr;
                }
                const float t = a[i]*d0 + a[3+i]*d1 + a[6+i]*d2;
                se += t * t;
            }
            sum += se;
        }
    }

    // ---- block reduction ----
    const int lane = tid & 63;
    const int wave = tid >> 6;
    #pragma unroll
    for (int off = 32; off > 0; off >>= 1) sum += __shfl_down(sum, off);
    if (lane == 0) redbuf[wave] = sum;
    __syncthreads();
    if (tid == 0) {
        float s = 0.0f;
        #pragma unroll
        for (int w = 0; w < BLOCK / 64; ++w) s += redbuf[w];
        partial[blockIdx.x] = s;
    }
}

__global__ __launch_bounds__(BLOCK) void rmse_finalize_kernel(
    const float* __restrict__ partial, int nPartial, float* __restrict__ out, int N)
{
    __shared__ float redbuf[BLOCK / 64];
    float sum = 0.0f;
    for (int i = threadIdx.x; i < nPartial; i += BLOCK) sum += partial[i];
    #pragma unroll
    for (int off = 32; off > 0; off >>= 1) sum += __shfl_down(sum, off);
    const int lane = threadIdx.x & 63;
    const int wave = threadIdx.x >> 6;
    if (lane == 0) redbuf[wave] = sum;
    __syncthreads();
    if (threadIdx.x == 0) {
        float s = 0.0f;
        #pragma unroll
        for (int w = 0; w < BLOCK / 64; ++w) s += redbuf[w];
        out[0] = sqrtf(s / (float)N) + 1e-8f;
    }
}

extern "C" void kernel_launch(void* const* d_in, const int* in_sizes, int n_in,
                              void* d_out, int out_size, void* d_ws, size_t ws_size,
                              hipStream_t stream) {
    const float* rot_kf  = (const float*)d_in[0];
    const float* pose_kf = (const float*)d_in[1];
    const float* rot_gt  = (const float*)d_in[2];
    const float* pose_gt = (const float*)d_in[3];
    float* out = (float*)d_out;
    float* partial = (float*)d_ws;

    const int N = in_sizes[1] / 3;   // pose_kf is [N,3]
    const int G = N >> 2;

    int grid = NBLOCKS;
    if (grid > G && G > 0) grid = G;
    const int wsCap = (int)(ws_size / sizeof(float));
    if (grid > wsCap) grid = wsCap;
    if (grid < 1) grid = 1;

    rmse_partial_kernel<<<grid, BLOCK, 0, stream>>>(rot_kf, pose_kf, rot_gt, pose_gt, partial, N);
    rmse_finalize_kernel<<<1, BLOCK, 0, stream>>>(partial, grid, out, N);
}

// Round 11
// 69.897 us; speedup vs baseline: 3.1841x; 1.0296x over previous
//
#include <hip/hip_runtime.h>
#include <math.h>

#define BLOCK 256
#define FPC   256                 // frames per chunk, one frame per thread
#define F4M   (FPC * 9 / 4)       // 576 float4 per rot matrix per chunk
#define NBLOCKS 2048              // 8 blocks/CU x 256 CU, all resident

__global__ __launch_bounds__(BLOCK, 8) void rmse_partial_kernel(
    const float* __restrict__ rot_kf, const float* __restrict__ pose_kf,
    const float* __restrict__ rot_gt, const float* __restrict__ pose_gt,
    float* __restrict__ partial, int N)
{
    // A and B staged together: 2 x 9216 B = 18432 B -> 8 blocks/CU
    __shared__ float ldsA[FPC * 9];
    __shared__ float ldsB[FPC * 9];
    __shared__ float redbuf[BLOCK / 64];

    const int tid = threadIdx.x;
    const long long totalRotF = (long long)N * 9;
    const int nChunks = (int)(((long long)N + FPC - 1) / FPC);

    float sum = 0.0f;

    for (int c = blockIdx.x; c < nChunks; c += gridDim.x) {
        const long long base4 = (long long)c * F4M;
        const int f = c * FPC + tid;

        // pose loads issued BEFORE the barrier: latency hides under staging
        float pk0 = 0.f, pk1 = 0.f, pk2 = 0.f, pg0 = 0.f, pg1 = 0.f, pg2 = 0.f;
        if (f < N) {
            const long long p = (long long)f * 3;
            pk0 = pose_kf[p + 0]; pk1 = pose_kf[p + 1]; pk2 = pose_kf[p + 2];
            pg0 = pose_gt[p + 0]; pg1 = pose_gt[p + 1]; pg2 = pose_gt[p + 2];
        }

        __syncthreads();   // protect LDS reads of previous iteration

        for (int i = tid; i < F4M; i += BLOCK) {
            const long long f4 = base4 + i;
            float4 v = make_float4(0.f, 0.f, 0.f, 0.f);
            if (f4 * 4 + 3 < totalRotF) v = reinterpret_cast<const float4*>(rot_kf)[f4];
            reinterpret_cast<float4*>(ldsA)[i] = v;
        }
        for (int i = tid; i < F4M; i += BLOCK) {
            const long long f4 = base4 + i;
            float4 v = make_float4(0.f, 0.f, 0.f, 0.f);
            if (f4 * 4 + 3 < totalRotF) v = reinterpret_cast<const float4*>(rot_gt)[f4];
            reinterpret_cast<float4*>(ldsB)[i] = v;
        }
        __syncthreads();

        if (f < N) {
            float a[9], b[9];
            #pragma unroll
            for (int j = 0; j < 9; ++j) a[j] = ldsA[tid * 9 + j];
            #pragma unroll
            for (int j = 0; j < 9; ++j) b[j] = ldsB[tid * 9 + j];

            const float d0 = pg0 - pk0;
            const float d1 = pg1 - pk1;
            const float d2 = pg2 - pk2;

            float se = 0.0f;
            #pragma unroll
            for (int i = 0; i < 3; ++i) {
                #pragma unroll
                for (int k = 0; k < 3; ++k) {
                    // R_rel[i][k] = sum_j A[j][i] * B[j][k]
                    float rr = a[i] * b[k] + a[3 + i] * b[3 + k] + a[6 + i] * b[6 + k];
                    rr -= (i == k) ? 1.0f : 0.0f;
                    se += rr * rr;
                }
                const float t = a[i] * d0 + a[3 + i] * d1 + a[6 + i] * d2;
                se += t * t;
            }
            sum += se;
        }
    }

    // ---- block reduction ----
    const int lane = tid & 63;
    const int wave = tid >> 6;
    #pragma unroll
    for (int off = 32; off > 0; off >>= 1) sum += __shfl_down(sum, off);
    if (lane == 0) redbuf[wave] = sum;
    __syncthreads();
    if (tid == 0) {
        float s = 0.0f;
        #pragma unroll
        for (int w = 0; w < BLOCK / 64; ++w) s += redbuf[w];
        partial[blockIdx.x] = s;
    }
}

__global__ __launch_bounds__(BLOCK) void rmse_finalize_kernel(
    const float* __restrict__ partial, int nPartial, float* __restrict__ out, int N)
{
    __shared__ float redbuf[BLOCK / 64];
    float sum = 0.0f;
    for (int i = threadIdx.x; i < nPartial; i += BLOCK) sum += partial[i];
    #pragma unroll
    for (int off = 32; off > 0; off >>= 1) sum += __shfl_down(sum, off);
    const int lane = threadIdx.x & 63;
    const int wave = threadIdx.x >> 6;
    if (lane == 0) redbuf[wave] = sum;
    __syncthreads();
    if (threadIdx.x == 0) {
        float s = 0.0f;
        #pragma unroll
        for (int w = 0; w < BLOCK / 64; ++w) s += redbuf[w];
        out[0] = sqrtf(s / (float)N) + 1e-8f;
    }
}

extern "C" void kernel_launch(void* const* d_in, const int* in_sizes, int n_in,
                              void* d_out, int out_size, void* d_ws, size_t ws_size,
                              hipStream_t stream) {
    const float* rot_kf  = (const float*)d_in[0];
    const float* pose_kf = (const float*)d_in[1];
    const float* rot_gt  = (const float*)d_in[2];
    const float* pose_gt = (const float*)d_in[3];
    float* out = (float*)d_out;
    float* partial = (float*)d_ws;

    const int N = in_sizes[1] / 3;   // pose_kf is [N,3]
    const int nChunks = (int)(((long long)N + FPC - 1) / FPC);

    int grid = NBLOCKS;
    if (grid > nChunks) grid = nChunks;
    const int wsCap = (int)(ws_size / sizeof(float));
    if (grid > wsCap) grid = wsCap;
    if (grid < 1) grid = 1;

    rmse_partial_kernel<<<grid, BLOCK, 0, stream>>>(rot_kf, pose_kf, rot_gt, pose_gt, partial, N);
    rmse_finalize_kernel<<<1, BLOCK, 0, stream>>>(partial, grid, out, N);
}